// Round 2
// baseline (950.632 us; speedup 1.0000x reference)
//
#include <hip/hip_runtime.h>
#include <cstdint>
#include <cstddef>

#define NN 100000
#define NE 1600000
#define NB ((NN + 63) / 64)   // 1563 blocks of 64 dst nodes

typedef __attribute__((ext_vector_type(8))) short bf16x8;
typedef __attribute__((ext_vector_type(4))) short bf16x4;
typedef __attribute__((ext_vector_type(4))) float f32x4;

// ---- d_ws byte layout ----
#define OFF_W    0u          // bf16 weights, 45056 B
#define OFF_CNT  45056u      // int counts[NN]
#define OFF_OFF  445056u     // int offsets[NN]
#define OFF_CUR  845120u     // int cursor[NN]
#define OFF_BS   1245120u    // int blocksums[128]
#define OFF_SE   1245632u    // int2 (src,eid)[NE]
#define OFF_SD   14045632u   // int dst[NE]
#define WS_NEED  20445632u

__device__ __forceinline__ short f2bf(float f) {
  uint32_t u = __builtin_bit_cast(uint32_t, f);
  u += 0x7FFFu + ((u >> 16) & 1u);   // RNE
  return (short)(u >> 16);
}

__device__ __forceinline__ float lrelu(float x) { return fmaxf(x, 0.1f * x); }

__device__ __forceinline__ void atomic_add_f32(float* p, float v) {
  __hip_atomic_fetch_add(p, v, __ATOMIC_RELAXED, __HIP_MEMORY_SCOPE_AGENT);
}

// Pre-transpose + bf16-convert weights: W1t[64][96], W2t[64][64], uW1t[64][128], uW2t[64][64]
__global__ void prep_kernel(const float* __restrict__ W1, const float* __restrict__ W2,
                            const float* __restrict__ uW1, const float* __restrict__ uW2,
                            short* __restrict__ ws) {
  int t = blockIdx.x * 256 + threadIdx.x;
  const int n1 = 64 * 96, n2 = 64 * 64, n3 = 64 * 128, n4 = 64 * 64;
  if (t < n1) { int c = t / 96, k = t % 96; ws[t] = f2bf(W1[k * 64 + c]); return; }
  t -= n1;
  if (t < n2) { int c = t / 64, k = t % 64; ws[n1 + t] = f2bf(W2[k * 64 + c]); return; }
  t -= n2;
  if (t < n3) { int c = t / 128, k = t % 128; ws[n1 + n2 + t] = f2bf(uW1[k * 64 + c]); return; }
  t -= n3;
  if (t < n4) { int c = t / 64, k = t % 64; ws[n1 + n2 + n3 + t] = f2bf(uW2[k * 64 + c]); return; }
}

// ---------- sort-by-dst machinery (runs every call; deterministic work) ----------
__global__ __launch_bounds__(256) void hist_kernel(const int* __restrict__ ei,
                                                   int* __restrict__ cnt) {
  int t = blockIdx.x * 256 + threadIdx.x;
  if (t < NE) atomicAdd(&cnt[ei[NE + t]], 1);
}

// per-1024-chunk exclusive scan + chunk totals
__global__ __launch_bounds__(1024) void scan_block_kernel(const int* __restrict__ cnt,
                                                          int* __restrict__ off,
                                                          int* __restrict__ bs) {
  __shared__ int wsum[16];
  const int tid = threadIdx.x, lane = tid & 63, w = tid >> 6;
  const int i = blockIdx.x * 1024 + tid;
  int v = (i < NN) ? cnt[i] : 0;
  int x = v;
#pragma unroll
  for (int d = 1; d < 64; d <<= 1) { int t = __shfl_up(x, d); if (lane >= d) x += t; }
  if (lane == 63) wsum[w] = x;
  __syncthreads();
  if (w == 0) {
    int s = (lane < 16) ? wsum[lane] : 0;
#pragma unroll
    for (int d = 1; d < 16; d <<= 1) { int t = __shfl_up(s, d); if (lane >= d) s += t; }
    if (lane < 16) wsum[lane] = s;   // inclusive wave totals
  }
  __syncthreads();
  int incl = x + ((w > 0) ? wsum[w - 1] : 0);
  if (i < NN) off[i] = incl - v;     // chunk-local exclusive
  if (tid == 1023) bs[blockIdx.x] = incl;
}

// add chunk bases (computed by in-block reduction of bs[0..c)) ; copy to cursor
__global__ __launch_bounds__(1024) void scan_add_kernel(int* __restrict__ off,
                                                        const int* __restrict__ bs,
                                                        int* __restrict__ cur) {
  __shared__ int sbase;
  const int tid = threadIdx.x, cB = blockIdx.x;
  if (tid < 64) {
    int s = 0;
    if (tid < cB && tid < 98) s += bs[tid];
    int j2 = tid + 64;
    if (j2 < cB && j2 < 98) s += bs[j2];
#pragma unroll
    for (int d = 1; d < 64; d <<= 1) s += __shfl_xor(s, d);
    if (tid == 0) sbase = s;
  }
  __syncthreads();
  const int base = sbase;
  const int i = cB * 1024 + tid;
  if (i < NN) { int o = off[i] + base; off[i] = o; cur[i] = o; }
}

__global__ __launch_bounds__(256) void scatter_kernel(const int* __restrict__ ei,
                                                      int* __restrict__ cur,
                                                      int2* __restrict__ sse,
                                                      int* __restrict__ sdst) {
  int t = blockIdx.x * 256 + threadIdx.x;
  if (t >= NE) return;
  int d = ei[NE + t];
  int pos = atomicAdd(&cur[d], 1);
  sse[pos] = make_int2(ei[t], t);
  sdst[pos] = d;
}

// ---------- fused: edge MLP tiles -> LDS agg -> node MLP+LN -> out ----------
__global__ __launch_bounds__(256) void fused_kernel(
    const float* __restrict__ nf, const float* __restrict__ ea,
    const float* __restrict__ ew,
    const int2* __restrict__ sse, const int* __restrict__ sdst,
    const int* __restrict__ off,
    const short* __restrict__ W1t, const float* __restrict__ b1,
    const short* __restrict__ W2t, const float* __restrict__ b2,
    const short* __restrict__ uW1t, const float* __restrict__ ub1,
    const float* __restrict__ gam, const float* __restrict__ bet,
    const short* __restrict__ uW2t, const float* __restrict__ ub2,
    float* __restrict__ out) {
  __shared__ float sAgg[64 * 68];      // agg[64 nodes][64+4 pad] f32; later reused as H-lds
  __shared__ uint4 hbuf_s[4][512];     // per-wave 8KB H staging (edge phase)
  __shared__ int   tdst[4][64];
  __shared__ float tw[4][64];

  const int tid = threadIdx.x;
  const int wv = tid >> 6, ln = tid & 63;
  const int c = ln & 15, g = ln >> 4;
  char* hb = (char*)hbuf_s[wv];
  const int nb = blockIdx.x * 64;

  for (int i = tid; i < 64 * 68; i += 256) sAgg[i] = 0.f;

  const int e0 = off[nb];
  const int nhi = nb + 64;
  const int e1 = (nhi >= NN) ? NE : off[nhi];
  __syncthreads();

  float b1v[4][4];
#pragma unroll
  for (int m = 0; m < 4; ++m)
#pragma unroll
    for (int r = 0; r < 4; ++r) b1v[m][r] = b1[16 * m + 4 * g + r];
  float b2v[4];
#pragma unroll
  for (int n = 0; n < 4; ++n) b2v[n] = b2[16 * n + c];

  // -------- edge phase: 64-edge tiles over this block's sorted range --------
  for (int t0 = e0 + wv * 64; t0 < e1; t0 += 256) {
    int src[4], eid[4];
#pragma unroll
    for (int n = 0; n < 4; ++n) {
      int slot = t0 + 16 * n + c;
      bool val = slot < e1;
      int2 se = val ? sse[slot] : make_int2(0, 0);
      src[n] = se.x; eid[n] = se.y;
      if (g == 0) {
        tdst[wv][16 * n + c] = val ? (sdst[slot] - nb) : 0;
        tw[wv][16 * n + c]   = val ? ew[se.y] : 0.f;
      }
    }

    f32x4 acc1[4][4];
#pragma unroll
    for (int i = 0; i < 4; ++i)
#pragma unroll
      for (int j = 0; j < 4; ++j) acc1[i][j] = f32x4{0.f, 0.f, 0.f, 0.f};

#pragma unroll
    for (int ks = 0; ks < 3; ++ks) {
      bf16x8 xf[4];
#pragma unroll
      for (int n = 0; n < 4; ++n) {
        const float* p = (ks < 2) ? (nf + (size_t)src[n] * 64 + ks * 32 + g * 8)
                                  : (ea + (size_t)eid[n] * 32 + g * 8);
        float4 u = *(const float4*)p;
        float4 v = *(const float4*)(p + 4);
        bf16x8 t;
        t[0] = f2bf(u.x); t[1] = f2bf(u.y); t[2] = f2bf(u.z); t[3] = f2bf(u.w);
        t[4] = f2bf(v.x); t[5] = f2bf(v.y); t[6] = f2bf(v.z); t[7] = f2bf(v.w);
        xf[n] = t;
      }
#pragma unroll
      for (int m = 0; m < 4; ++m) {
        bf16x8 wf = *(const bf16x8*)(W1t + (size_t)(16 * m + c) * 96 + ks * 32 + g * 8);
#pragma unroll
        for (int n = 0; n < 4; ++n)
          acc1[m][n] = __builtin_amdgcn_mfma_f32_16x16x32_bf16(wf, xf[n], acc1[m][n], 0, 0, 0);
      }
    }

    // bias + leaky + transposed H store (XOR-swizzled, wave-private)
#pragma unroll
    for (int m = 0; m < 4; ++m) {
      const int h0 = 16 * m + 4 * g;
#pragma unroll
      for (int n = 0; n < 4; ++n) {
        const int e = 16 * n + c;
        bf16x4 pk;
#pragma unroll
        for (int r = 0; r < 4; ++r) pk[r] = f2bf(lrelu(acc1[m][n][r] + b1v[m][r]));
        const int byte = e * 128 + ((h0 * 2) ^ ((e & 7) << 4));
        *(bf16x4*)(hb + byte) = pk;
      }
    }

    f32x4 acc2[4][4];
#pragma unroll
    for (int i = 0; i < 4; ++i)
#pragma unroll
      for (int j = 0; j < 4; ++j) acc2[i][j] = f32x4{0.f, 0.f, 0.f, 0.f};

#pragma unroll
    for (int ks = 0; ks < 2; ++ks) {
      bf16x8 hf[4];
#pragma unroll
      for (int m = 0; m < 4; ++m) {
        const int e = 16 * m + c;
        const int byte = e * 128 + ((ks * 64 + g * 16) ^ ((e & 7) << 4));
        hf[m] = *(const bf16x8*)(hb + byte);
      }
#pragma unroll
      for (int n = 0; n < 4; ++n) {
        bf16x8 wf = *(const bf16x8*)(W2t + (size_t)(16 * n + c) * 64 + ks * 32 + g * 8);
#pragma unroll
        for (int m = 0; m < 4; ++m)
          acc2[m][n] = __builtin_amdgcn_mfma_f32_16x16x32_bf16(hf[m], wf, acc2[m][n], 0, 0, 0);
      }
    }

    // epilogue: weighted message -> LDS atomic aggregate
#pragma unroll
    for (int m = 0; m < 4; ++m)
#pragma unroll
      for (int r = 0; r < 4; ++r) {
        const int s2 = 16 * m + 4 * g + r;
        const int dl = tdst[wv][s2];
        const float w = tw[wv][s2];
#pragma unroll
        for (int n = 0; n < 4; ++n)
          atomicAdd(&sAgg[dl * 68 + c + 16 * n], (acc2[m][n][r] + b2v[n]) * w);
      }
  }
  __syncthreads();

  // -------- node phase: wave wv owns node col-tile wv (16 nodes) --------
  const int nloc = 16 * wv + c;
  const int nodec = nb + nloc;
  const int ncl = (nodec < NN) ? nodec : (NN - 1);

  f32x4 un[4];
#pragma unroll
  for (int m = 0; m < 4; ++m) un[m] = f32x4{0.f, 0.f, 0.f, 0.f};

#pragma unroll
  for (int ks = 0; ks < 4; ++ks) {
    bf16x8 xf;
    float4 u, v;
    if (ks < 2) {
      const float* p = nf + (size_t)ncl * 64 + ks * 32 + g * 8;
      u = *(const float4*)p; v = *(const float4*)(p + 4);
    } else {
      const float* p = sAgg + nloc * 68 + (ks - 2) * 32 + g * 8;
      u = *(const float4*)p; v = *(const float4*)(p + 4);
    }
    xf[0] = f2bf(u.x); xf[1] = f2bf(u.y); xf[2] = f2bf(u.z); xf[3] = f2bf(u.w);
    xf[4] = f2bf(v.x); xf[5] = f2bf(v.y); xf[6] = f2bf(v.z); xf[7] = f2bf(v.w);
#pragma unroll
    for (int m = 0; m < 4; ++m) {
      bf16x8 wf = *(const bf16x8*)(uW1t + (size_t)(16 * m + c) * 128 + ks * 32 + g * 8);
      un[m] = __builtin_amdgcn_mfma_f32_16x16x32_bf16(wf, xf, un[m], 0, 0, 0);
    }
  }

  float b1n[4][4], gn[4][4], bn[4][4];
#pragma unroll
  for (int m = 0; m < 4; ++m)
#pragma unroll
    for (int r = 0; r < 4; ++r) {
      int h = 16 * m + 4 * g + r;
      b1n[m][r] = ub1[h]; gn[m][r] = gam[h]; bn[m][r] = bet[h];
    }

  float s = 0.f;
#pragma unroll
  for (int m = 0; m < 4; ++m)
#pragma unroll
    for (int r = 0; r < 4; ++r) { un[m][r] += b1n[m][r]; s += un[m][r]; }
  s += __shfl_xor(s, 16);
  s += __shfl_xor(s, 32);
  const float mu = s * 0.015625f;
  float vs = 0.f;
#pragma unroll
  for (int m = 0; m < 4; ++m)
#pragma unroll
    for (int r = 0; r < 4; ++r) { float d = un[m][r] - mu; vs += d * d; }
  vs += __shfl_xor(vs, 16);
  vs += __shfl_xor(vs, 32);
  const float rstd = rsqrtf(vs * 0.015625f + 1e-5f);

  bf16x4 pk[4];
#pragma unroll
  for (int m = 0; m < 4; ++m)
#pragma unroll
    for (int r = 0; r < 4; ++r)
      pk[m][r] = f2bf(lrelu((un[m][r] - mu) * rstd * gn[m][r] + bn[m][r]));

  __syncthreads();   // all sAgg reads done -> reuse as H buffer
  char* hb2 = (char*)sAgg;
#pragma unroll
  for (int m = 0; m < 4; ++m) {
    const int h0 = 16 * m + 4 * g;
    const int byte = nloc * 128 + ((h0 * 2) ^ ((nloc & 7) << 4));
    *(bf16x4*)(hb2 + byte) = pk[m];
  }
  __syncthreads();

  f32x4 ac[4];
#pragma unroll
  for (int n = 0; n < 4; ++n) ac[n] = f32x4{0.f, 0.f, 0.f, 0.f};
#pragma unroll
  for (int ks = 0; ks < 2; ++ks) {
    const int byte = nloc * 128 + ((ks * 64 + g * 16) ^ ((nloc & 7) << 4));
    bf16x8 hf = *(const bf16x8*)(hb2 + byte);
#pragma unroll
    for (int n = 0; n < 4; ++n) {
      bf16x8 wf = *(const bf16x8*)(uW2t + (size_t)(16 * n + c) * 64 + ks * 32 + g * 8);
      ac[n] = __builtin_amdgcn_mfma_f32_16x16x32_bf16(hf, wf, ac[n], 0, 0, 0);
    }
  }

  float b2n[4];
#pragma unroll
  for (int n = 0; n < 4; ++n) b2n[n] = ub2[16 * n + c];
#pragma unroll
  for (int r = 0; r < 4; ++r) {
    const int node = nb + 16 * wv + 4 * g + r;
    if (node < NN) {
      float* op = out + (size_t)node * 64 + c;
#pragma unroll
      for (int n = 0; n < 4; ++n) op[16 * n] = ac[n][r] + b2n[n];
    }
  }
}

// ================= fallback path (ws too small): R1 kernels =================
__global__ __launch_bounds__(256) void edge_kernel(
    const float* __restrict__ nf, const int* __restrict__ ei,
    const float* __restrict__ ea, const float* __restrict__ ew,
    const short* __restrict__ W1t, const float* __restrict__ b1,
    const short* __restrict__ W2t, const float* __restrict__ b2,
    float* __restrict__ agg) {
  __shared__ uint4 hbuf_s[4][512];
  const int tid = threadIdx.x;
  const int wv = tid >> 6, ln = tid & 63;
  const int c = ln & 15, g = ln >> 4;
  char* hb = (char*)hbuf_s[wv];
  const long base = ((long)blockIdx.x * 4 + wv) * 64;

  int eid[4], srcn[4];
#pragma unroll
  for (int n = 0; n < 4; ++n) {
    eid[n] = (int)base + 16 * n + c;
    srcn[n] = ei[eid[n]];
  }
  f32x4 acc1[4][4];
#pragma unroll
  for (int i = 0; i < 4; ++i)
#pragma unroll
    for (int j = 0; j < 4; ++j) acc1[i][j] = f32x4{0.f, 0.f, 0.f, 0.f};
#pragma unroll
  for (int ks = 0; ks < 3; ++ks) {
    bf16x8 xf[4];
#pragma unroll
    for (int n = 0; n < 4; ++n) {
      const float* p = (ks < 2) ? (nf + (size_t)srcn[n] * 64 + ks * 32 + g * 8)
                                : (ea + (size_t)eid[n] * 32 + g * 8);
      float4 u = *(const float4*)p;
      float4 v = *(const float4*)(p + 4);
      bf16x8 t;
      t[0] = f2bf(u.x); t[1] = f2bf(u.y); t[2] = f2bf(u.z); t[3] = f2bf(u.w);
      t[4] = f2bf(v.x); t[5] = f2bf(v.y); t[6] = f2bf(v.z); t[7] = f2bf(v.w);
      xf[n] = t;
    }
#pragma unroll
    for (int m = 0; m < 4; ++m) {
      bf16x8 wf = *(const bf16x8*)(W1t + (size_t)(16 * m + c) * 96 + ks * 32 + g * 8);
#pragma unroll
      for (int n = 0; n < 4; ++n)
        acc1[m][n] = __builtin_amdgcn_mfma_f32_16x16x32_bf16(wf, xf[n], acc1[m][n], 0, 0, 0);
    }
  }
  float b1v[4][4];
#pragma unroll
  for (int m = 0; m < 4; ++m)
#pragma unroll
    for (int r = 0; r < 4; ++r) b1v[m][r] = b1[16 * m + 4 * g + r];
#pragma unroll
  for (int m = 0; m < 4; ++m) {
    const int h0 = 16 * m + 4 * g;
#pragma unroll
    for (int n = 0; n < 4; ++n) {
      const int e = 16 * n + c;
      bf16x4 pk;
#pragma unroll
      for (int r = 0; r < 4; ++r) pk[r] = f2bf(lrelu(acc1[m][n][r] + b1v[m][r]));
      const int byte = e * 128 + ((h0 * 2) ^ ((e & 7) << 4));
      *(bf16x4*)(hb + byte) = pk;
    }
  }
  f32x4 acc2[4][4];
#pragma unroll
  for (int i = 0; i < 4; ++i)
#pragma unroll
    for (int j = 0; j < 4; ++j) acc2[i][j] = f32x4{0.f, 0.f, 0.f, 0.f};
#pragma unroll
  for (int ks = 0; ks < 2; ++ks) {
    bf16x8 hf[4];
#pragma unroll
    for (int m = 0; m < 4; ++m) {
      const int e = 16 * m + c;
      const int byte = e * 128 + ((ks * 64 + g * 16) ^ ((e & 7) << 4));
      hf[m] = *(const bf16x8*)(hb + byte);
    }
#pragma unroll
    for (int n = 0; n < 4; ++n) {
      bf16x8 wf = *(const bf16x8*)(W2t + (size_t)(16 * n + c) * 64 + ks * 32 + g * 8);
#pragma unroll
      for (int m = 0; m < 4; ++m)
        acc2[m][n] = __builtin_amdgcn_mfma_f32_16x16x32_bf16(hf[m], wf, acc2[m][n], 0, 0, 0);
    }
  }
  float b2v[4];
#pragma unroll
  for (int n = 0; n < 4; ++n) b2v[n] = b2[16 * n + c];
#pragma unroll
  for (int m = 0; m < 4; ++m)
#pragma unroll
    for (int r = 0; r < 4; ++r) {
      const long e = base + 16 * m + 4 * g + r;
      const float w = ew[e];
      const int dst = ei[NE + e];
      float* ab = agg + (size_t)dst * 64 + c;
#pragma unroll
      for (int n = 0; n < 4; ++n)
        atomic_add_f32(ab + 16 * n, (acc2[m][n][r] + b2v[n]) * w);
    }
}

__global__ __launch_bounds__(256) void node_kernel(
    const float* __restrict__ nf,
    const short* __restrict__ W1t, const float* __restrict__ b1,
    const float* __restrict__ gam, const float* __restrict__ bet,
    const short* __restrict__ W2t, const float* __restrict__ b2,
    float* __restrict__ io) {
  __shared__ uint4 hbuf_s[4][512];
  const int tid = threadIdx.x;
  const int wv = tid >> 6, ln = tid & 63;
  const int c = ln & 15, g = ln >> 4;
  char* hb = (char*)hbuf_s[wv];
  const long base = ((long)blockIdx.x * 4 + wv) * 64;

  int nid[4];
#pragma unroll
  for (int n = 0; n < 4; ++n) {
    long r = base + 16 * n + c;
    nid[n] = (r < NN) ? (int)r : (NN - 1);
  }
  f32x4 acc1[4][4];
#pragma unroll
  for (int i = 0; i < 4; ++i)
#pragma unroll
    for (int j = 0; j < 4; ++j) acc1[i][j] = f32x4{0.f, 0.f, 0.f, 0.f};
#pragma unroll
  for (int ks = 0; ks < 4; ++ks) {
    bf16x8 xf[4];
#pragma unroll
    for (int n = 0; n < 4; ++n) {
      const float* p = (ks < 2) ? (nf + (size_t)nid[n] * 64 + ks * 32 + g * 8)
                                : (io + (size_t)nid[n] * 64 + (ks - 2) * 32 + g * 8);
      float4 u = *(const float4*)p;
      float4 v = *(const float4*)(p + 4);
      bf16x8 t;
      t[0] = f2bf(u.x); t[1] = f2bf(u.y); t[2] = f2bf(u.z); t[3] = f2bf(u.w);
      t[4] = f2bf(v.x); t[5] = f2bf(v.y); t[6] = f2bf(v.z); t[7] = f2bf(v.w);
      xf[n] = t;
    }
#pragma unroll
    for (int m = 0; m < 4; ++m) {
      bf16x8 wf = *(const bf16x8*)(W1t + (size_t)(16 * m + c) * 128 + ks * 32 + g * 8);
#pragma unroll
      for (int n = 0; n < 4; ++n)
        acc1[m][n] = __builtin_amdgcn_mfma_f32_16x16x32_bf16(wf, xf[n], acc1[m][n], 0, 0, 0);
    }
  }
  float b1v[4][4], gv[4][4], bv[4][4];
#pragma unroll
  for (int m = 0; m < 4; ++m)
#pragma unroll
    for (int r = 0; r < 4; ++r) {
      int h = 16 * m + 4 * g + r;
      b1v[m][r] = b1[h]; gv[m][r] = gam[h]; bv[m][r] = bet[h];
    }
#pragma unroll
  for (int n = 0; n < 4; ++n) {
    float s = 0.f;
#pragma unroll
    for (int m = 0; m < 4; ++m)
#pragma unroll
      for (int r = 0; r < 4; ++r) { acc1[m][n][r] += b1v[m][r]; s += acc1[m][n][r]; }
    s += __shfl_xor(s, 16);
    s += __shfl_xor(s, 32);
    const float mu = s * 0.015625f;
    float vs = 0.f;
#pragma unroll
    for (int m = 0; m < 4; ++m)
#pragma unroll
      for (int r = 0; r < 4; ++r) { float d = acc1[m][n][r] - mu; vs += d * d; }
    vs += __shfl_xor(vs, 16);
    vs += __shfl_xor(vs, 32);
    const float rstd = rsqrtf(vs * 0.015625f + 1e-5f);
    const int e = 16 * n + c;
#pragma unroll
    for (int m = 0; m < 4; ++m) {
      bf16x4 pk;
#pragma unroll
      for (int r = 0; r < 4; ++r)
        pk[r] = f2bf(lrelu((acc1[m][n][r] - mu) * rstd * gv[m][r] + bv[m][r]));
      const int byte = e * 128 + (((16 * m + 4 * g) * 2) ^ ((e & 7) << 4));
      *(bf16x4*)(hb + byte) = pk;
    }
  }
  f32x4 acc2[4][4];
#pragma unroll
  for (int i = 0; i < 4; ++i)
#pragma unroll
    for (int j = 0; j < 4; ++j) acc2[i][j] = f32x4{0.f, 0.f, 0.f, 0.f};
#pragma unroll
  for (int ks = 0; ks < 2; ++ks) {
    bf16x8 hf[4];
#pragma unroll
    for (int m = 0; m < 4; ++m) {
      const int e = 16 * m + c;
      const int byte = e * 128 + ((ks * 64 + g * 16) ^ ((e & 7) << 4));
      hf[m] = *(const bf16x8*)(hb + byte);
    }
#pragma unroll
    for (int n = 0; n < 4; ++n) {
      bf16x8 wf = *(const bf16x8*)(W2t + (size_t)(16 * n + c) * 64 + ks * 32 + g * 8);
#pragma unroll
      for (int m = 0; m < 4; ++m)
        acc2[m][n] = __builtin_amdgcn_mfma_f32_16x16x32_bf16(hf[m], wf, acc2[m][n], 0, 0, 0);
    }
  }
  float b2v[4];
#pragma unroll
  for (int n = 0; n < 4; ++n) b2v[n] = b2[16 * n + c];
#pragma unroll
  for (int m = 0; m < 4; ++m)
#pragma unroll
    for (int r = 0; r < 4; ++r) {
      const long node = base + 16 * m + 4 * g + r;
      if (node < NN) {
        float* op = io + (size_t)node * 64 + c;
#pragma unroll
        for (int n = 0; n < 4; ++n) op[16 * n] = acc2[m][n][r] + b2v[n];
      }
    }
}

extern "C" void kernel_launch(void* const* d_in, const int* in_sizes, int n_in,
                              void* d_out, int out_size, void* d_ws, size_t ws_size,
                              hipStream_t stream) {
  const float* nf  = (const float*)d_in[0];
  const int*   ei  = (const int*)d_in[1];
  const float* ea  = (const float*)d_in[2];
  const float* ew  = (const float*)d_in[3];
  const float* mW1 = (const float*)d_in[4];
  const float* mb1 = (const float*)d_in[5];
  const float* mW2 = (const float*)d_in[6];
  const float* mb2 = (const float*)d_in[7];
  const float* uW1 = (const float*)d_in[8];
  const float* ub1 = (const float*)d_in[9];
  const float* lng = (const float*)d_in[10];
  const float* lnb = (const float*)d_in[11];
  const float* uW2 = (const float*)d_in[12];
  const float* ub2 = (const float*)d_in[13];
  float* io = (float*)d_out;
  char* ws = (char*)d_ws;

  short* Wall = (short*)(ws + OFF_W);
  prep_kernel<<<88, 256, 0, stream>>>(mW1, mW2, uW1, uW2, Wall);
  const short* W1t  = Wall;
  const short* W2t  = Wall + 64 * 96;
  const short* uW1t = Wall + 64 * 96 + 64 * 64;
  const short* uW2t = uW1t + 64 * 128;

  if (ws_size >= (size_t)WS_NEED) {
    int*  cnt  = (int*)(ws + OFF_CNT);
    int*  off  = (int*)(ws + OFF_OFF);
    int*  cur  = (int*)(ws + OFF_CUR);
    int*  bs   = (int*)(ws + OFF_BS);
    int2* sse  = (int2*)(ws + OFF_SE);
    int*  sdst = (int*)(ws + OFF_SD);

    hipMemsetAsync(cnt, 0, (size_t)NN * sizeof(int), stream);
    hist_kernel<<<NE / 256, 256, 0, stream>>>(ei, cnt);
    scan_block_kernel<<<98, 1024, 0, stream>>>(cnt, off, bs);
    scan_add_kernel<<<98, 1024, 0, stream>>>(off, bs, cur);
    scatter_kernel<<<NE / 256, 256, 0, stream>>>(ei, cur, sse, sdst);
    fused_kernel<<<NB, 256, 0, stream>>>(nf, ea, ew, sse, sdst, off,
                                         W1t, mb1, W2t, mb2,
                                         uW1t, ub1, lng, lnb, uW2t, ub2, io);
  } else {
    hipMemsetAsync(d_out, 0, (size_t)NN * 64 * sizeof(float), stream);
    edge_kernel<<<NE / 256, 256, 0, stream>>>(nf, ei, ea, ew, W1t, mb1, W2t, mb2, io);
    node_kernel<<<(NN + 255) / 256, 256, 0, stream>>>(nf, uW1t, ub1, lng, lnb, uW2t, ub2, io);
  }
}

// Round 7
// 515.252 us; speedup vs baseline: 1.8450x; 1.8450x over previous
//
#include <hip/hip_runtime.h>
#include <cstdint>
#include <cstddef>

#define NN 100000
#define NE 1600000

#define QSCALE 262144.0f            // 2^18 fixed point: exact-commutative agg
#define QINV   3.814697265625e-06f  // 2^-18

typedef __attribute__((ext_vector_type(8))) short bf16x8;
typedef __attribute__((ext_vector_type(4))) short bf16x4;
typedef __attribute__((ext_vector_type(4))) float f32x4;

// ---- d_ws byte layout (proven to fit since R2) ----
#define OFF_W    0u          // bf16 weights, 45056 B
#define OFF_CNT  45056u      // int counts[NN]
#define OFF_OFF  445056u     // int offsets[NN]
#define OFF_CUR  845120u     // int cursor[NN]
#define OFF_BS   1245120u    // int blocksums[128]
#define OFF_SE   1245632u    // int2 (src,eid)[NE]
#define OFF_SD   14045632u   // int dst[NE]
#define WS_NEED  20445632u

__device__ __forceinline__ short f2bf(float f) {
  uint32_t u = __builtin_bit_cast(uint32_t, f);
  u += 0x7FFFu + ((u >> 16) & 1u);   // RNE
  return (short)(u >> 16);
}

__device__ __forceinline__ float lrelu(float x) { return fmaxf(x, 0.1f * x); }

__device__ __forceinline__ void atomic_add_f32(float* p, float v) {
  __hip_atomic_fetch_add(p, v, __ATOMIC_RELAXED, __HIP_MEMORY_SCOPE_AGENT);
}

// Pre-transpose + bf16-convert weights: W1t[64][96], W2t[64][64], uW1t[64][128], uW2t[64][64]
__global__ void prep_kernel(const float* __restrict__ W1, const float* __restrict__ W2,
                            const float* __restrict__ uW1, const float* __restrict__ uW2,
                            short* __restrict__ ws) {
  int t = blockIdx.x * 256 + threadIdx.x;
  const int n1 = 64 * 96, n2 = 64 * 64, n3 = 64 * 128, n4 = 64 * 64;
  if (t < n1) { int c = t / 96, k = t % 96; ws[t] = f2bf(W1[k * 64 + c]); return; }
  t -= n1;
  if (t < n2) { int c = t / 64, k = t % 64; ws[n1 + t] = f2bf(W2[k * 64 + c]); return; }
  t -= n2;
  if (t < n3) { int c = t / 128, k = t % 128; ws[n1 + n2 + t] = f2bf(uW1[k * 64 + c]); return; }
  t -= n3;
  if (t < n4) { int c = t / 64, k = t % 64; ws[n1 + n2 + n3 + t] = f2bf(uW2[k * 64 + c]); return; }
}

// ---------- sort-by-dst machinery ----------
__global__ __launch_bounds__(256) void hist_kernel(const int* __restrict__ ei,
                                                   int* __restrict__ cnt) {
  int t = blockIdx.x * 256 + threadIdx.x;
  if (t < NE) atomicAdd(&cnt[ei[NE + t]], 1);
}

__global__ __launch_bounds__(1024) void scan_block_kernel(const int* __restrict__ cnt,
                                                          int* __restrict__ off,
                                                          int* __restrict__ bs) {
  __shared__ int wsum[16];
  const int tid = threadIdx.x, lane = tid & 63, w = tid >> 6;
  const int i = blockIdx.x * 1024 + tid;
  int v = (i < NN) ? cnt[i] : 0;
  int x = v;
#pragma unroll
  for (int d = 1; d < 64; d <<= 1) { int t = __shfl_up(x, d); if (lane >= d) x += t; }
  if (lane == 63) wsum[w] = x;
  __syncthreads();
  if (w == 0) {
    int s = (lane < 16) ? wsum[lane] : 0;
#pragma unroll
    for (int d = 1; d < 16; d <<= 1) { int t = __shfl_up(s, d); if (lane >= d) s += t; }
    if (lane < 16) wsum[lane] = s;
  }
  __syncthreads();
  int incl = x + ((w > 0) ? wsum[w - 1] : 0);
  if (i < NN) off[i] = incl - v;
  if (tid == 1023) bs[blockIdx.x] = incl;
}

__global__ __launch_bounds__(1024) void scan_add_kernel(int* __restrict__ off,
                                                        const int* __restrict__ bs,
                                                        int* __restrict__ cur) {
  __shared__ int sbase;
  const int tid = threadIdx.x, cB = blockIdx.x;
  if (tid < 64) {
    int s = 0;
    if (tid < cB && tid < 98) s += bs[tid];
    int j2 = tid + 64;
    if (j2 < cB && j2 < 98) s += bs[j2];
#pragma unroll
    for (int d = 1; d < 64; d <<= 1) s += __shfl_xor(s, d);
    if (tid == 0) sbase = s;
  }
  __syncthreads();
  const int base = sbase;
  const int i = cB * 1024 + tid;
  if (i < NN) { int o = off[i] + base; off[i] = o; cur[i] = o; }
}

__global__ __launch_bounds__(256) void scatter_kernel(const int* __restrict__ ei,
                                                      int* __restrict__ cur,
                                                      int2* __restrict__ sse,
                                                      int* __restrict__ sdst) {
  int t = blockIdx.x * 256 + threadIdx.x;
  if (t >= NE) return;
  int d = ei[NE + t];
  int pos = atomicAdd(&cur[d], 1);
  sse[pos] = make_int2(ei[t], t);
  sdst[pos] = d;
}

// ---------- sortruns: canonicalize each dst run by eid ----------
// Makes sse content bitwise-deterministic per ADDRESS (not just per multiset),
// so any stale cache line equals current data. d_ws becomes a pure function
// of the inputs at every point of its lifecycle.
__global__ __launch_bounds__(256) void sortruns_kernel(const int* __restrict__ off,
                                                       const int* __restrict__ cnt,
                                                       int2* __restrict__ sse) {
  __shared__ int2 stage[4][512];
  const int wv = threadIdx.x >> 6, ln = threadIdx.x & 63;
  const int d = blockIdx.x * 4 + wv;
  if (d >= NN) return;
  const int s = off[d], n = cnt[d];
  if (n <= 1) return;
  if (n <= 64) {
    int2 v = make_int2(0, 0);
    int key = 0x7fffffff;
    if (ln < n) { v = sse[s + ln]; key = v.y; }
    int rank = 0;
#pragma unroll
    for (int j = 0; j < 64; ++j) {
      int kj = __shfl(key, j);
      rank += (kj < key) ? 1 : 0;
    }
    if (ln < n) sse[s + rank] = v;
  } else if (n <= 512) {
    for (int i = ln; i < n; i += 64) stage[wv][i] = sse[s + i];
    for (int i = ln; i < n; i += 64) {
      int2 v = stage[wv][i];
      int rank = 0;
      for (int j = 0; j < n; ++j) rank += (stage[wv][j].y < v.y) ? 1 : 0;
      sse[s + rank] = v;
    }
  }
}

// ---------- fused kernel: block owns 32 dsts; edge MLP -> LDS int agg -> node MLP ----------
// d_out is written EXACTLY ONCE per element (node phase) and read by nobody.
// agg never leaves LDS (R2's proven-replay-safe structure, efficient geometry).
__global__ __launch_bounds__(128) void fused_kernel(
    const float* __restrict__ nf, const float* __restrict__ ea,
    const float* __restrict__ ew,
    const int2* __restrict__ sse, const int* __restrict__ sdst,
    const int* __restrict__ off,
    const short* __restrict__ W1t, const float* __restrict__ b1,
    const short* __restrict__ W2t, const float* __restrict__ b2,
    const short* __restrict__ uW1t, const float* __restrict__ ub1,
    const float* __restrict__ gam, const float* __restrict__ bet,
    const short* __restrict__ uW2t, const float* __restrict__ ub2,
    float* __restrict__ out) {
  __shared__ __align__(16) char hbuf[2][8192];   // per-wave H staging
  __shared__ int   sAgg[32 * 65];                // fixed-point agg [32 dst][64+1]
  __shared__ int   tdstS[2][64];
  __shared__ float twS[2][64];

  const int tid = threadIdx.x;
  const int wv = tid >> 6, ln = tid & 63;
  const int c = ln & 15, g = ln >> 4;
  char* hb = hbuf[wv];
  const int nb = blockIdx.x * 32;

  for (int i = tid; i < 32 * 65; i += 128) sAgg[i] = 0;

  const int e0 = off[nb];
  const int e1 = (nb + 32 >= NN) ? NE : off[nb + 32];
  __syncthreads();

  float b1v[4][4];
#pragma unroll
  for (int m = 0; m < 4; ++m)
#pragma unroll
    for (int r = 0; r < 4; ++r) b1v[m][r] = b1[16 * m + 4 * g + r];
  float b2v[4];
#pragma unroll
  for (int n = 0; n < 4; ++n) b2v[n] = b2[16 * n + c];

  // -------- edge phase: 64-edge tiles (waves interleaved) --------
  for (int t0 = e0 + wv * 64; t0 < e1; t0 += 128) {
    {
      int slot = t0 + ln;
      bool val = slot < e1;
      int2 se = val ? sse[slot] : make_int2(0, 0);
      tdstS[wv][ln] = val ? (sdst[slot] - nb) : 0;
      twS[wv][ln]   = val ? ew[se.y] : 0.f;
    }
    int src[4], eid[4];
#pragma unroll
    for (int n = 0; n < 4; ++n) {
      int slot = t0 + 16 * n + c;
      if (slot < e1) { int2 se = sse[slot]; src[n] = se.x; eid[n] = se.y; }
      else           { src[n] = 0; eid[n] = 0; }
    }

    f32x4 acc1[4][4];
#pragma unroll
    for (int i = 0; i < 4; ++i)
#pragma unroll
      for (int j = 0; j < 4; ++j) acc1[i][j] = f32x4{0.f, 0.f, 0.f, 0.f};

#pragma unroll
    for (int ks = 0; ks < 3; ++ks) {
      bf16x8 xf[4];
#pragma unroll
      for (int n = 0; n < 4; ++n) {
        const float* p = (ks < 2) ? (nf + (size_t)src[n] * 64 + ks * 32 + g * 8)
                                  : (ea + (size_t)eid[n] * 32 + g * 8);
        float4 u = *(const float4*)p;
        float4 v = *(const float4*)(p + 4);
        bf16x8 t;
        t[0] = f2bf(u.x); t[1] = f2bf(u.y); t[2] = f2bf(u.z); t[3] = f2bf(u.w);
        t[4] = f2bf(v.x); t[5] = f2bf(v.y); t[6] = f2bf(v.z); t[7] = f2bf(v.w);
        xf[n] = t;
      }
#pragma unroll
      for (int m = 0; m < 4; ++m) {
        bf16x8 wf = *(const bf16x8*)(W1t + (size_t)(16 * m + c) * 96 + ks * 32 + g * 8);
#pragma unroll
        for (int n = 0; n < 4; ++n)
          acc1[m][n] = __builtin_amdgcn_mfma_f32_16x16x32_bf16(wf, xf[n], acc1[m][n], 0, 0, 0);
      }
    }

#pragma unroll
    for (int m = 0; m < 4; ++m) {
      const int h0 = 16 * m + 4 * g;
#pragma unroll
      for (int n = 0; n < 4; ++n) {
        const int e = 16 * n + c;
        bf16x4 pk;
#pragma unroll
        for (int r = 0; r < 4; ++r) pk[r] = f2bf(lrelu(acc1[m][n][r] + b1v[m][r]));
        const int byte = e * 128 + ((h0 * 2) ^ ((e & 7) << 4));
        *(bf16x4*)(hb + byte) = pk;
      }
    }

    f32x4 acc2[4][4];
#pragma unroll
    for (int i = 0; i < 4; ++i)
#pragma unroll
      for (int j = 0; j < 4; ++j) acc2[i][j] = f32x4{0.f, 0.f, 0.f, 0.f};
#pragma unroll
    for (int ks = 0; ks < 2; ++ks) {
      bf16x8 hf[4];
#pragma unroll
      for (int m = 0; m < 4; ++m) {
        const int e = 16 * m + c;
        const int byte = e * 128 + ((ks * 64 + g * 16) ^ ((e & 7) << 4));
        hf[m] = *(const bf16x8*)(hb + byte);
      }
#pragma unroll
      for (int n = 0; n < 4; ++n) {
        bf16x8 wf = *(const bf16x8*)(W2t + (size_t)(16 * n + c) * 64 + ks * 32 + g * 8);
#pragma unroll
        for (int m = 0; m < 4; ++m)
          acc2[m][n] = __builtin_amdgcn_mfma_f32_16x16x32_bf16(hf[m], wf, acc2[m][n], 0, 0, 0);
      }
    }

#pragma unroll
    for (int m = 0; m < 4; ++m)
#pragma unroll
      for (int r = 0; r < 4; ++r) {
        const int el = 16 * m + 4 * g + r;
        const int dl = tdstS[wv][el];
        const float w = twS[wv][el];
#pragma unroll
        for (int n = 0; n < 4; ++n)
          atomicAdd(&sAgg[dl * 65 + 16 * n + c],
                    __float2int_rn((acc2[m][n][r] + b2v[n]) * w * QSCALE));
      }
  }
  __syncthreads();   // all agg atomics complete; sAgg final

  // -------- node phase: wave wv owns 16 nodes [nb+16wv, nb+16wv+16) --------
  const int nodeN = nb + 16 * wv + c;   // this lane's node column

  f32x4 un[4];
#pragma unroll
  for (int m = 0; m < 4; ++m) un[m] = f32x4{0.f, 0.f, 0.f, 0.f};

#pragma unroll
  for (int ks = 0; ks < 4; ++ks) {
    bf16x8 xf;
    if (ks < 2) {
      const float* p = nf + (size_t)nodeN * 64 + ks * 32 + g * 8;
      float4 u = *(const float4*)p;
      float4 v = *(const float4*)(p + 4);
      xf[0] = f2bf(u.x); xf[1] = f2bf(u.y); xf[2] = f2bf(u.z); xf[3] = f2bf(u.w);
      xf[4] = f2bf(v.x); xf[5] = f2bf(v.y); xf[6] = f2bf(v.z); xf[7] = f2bf(v.w);
    } else {
      const int* p = sAgg + (16 * wv + c) * 65 + (ks - 2) * 32 + g * 8;
#pragma unroll
      for (int j = 0; j < 8; ++j) xf[j] = f2bf((float)p[j] * QINV);
    }
#pragma unroll
    for (int m = 0; m < 4; ++m) {
      bf16x8 wf = *(const bf16x8*)(uW1t + (size_t)(16 * m + c) * 128 + ks * 32 + g * 8);
      un[m] = __builtin_amdgcn_mfma_f32_16x16x32_bf16(wf, xf, un[m], 0, 0, 0);
    }
  }

  float b1n[4][4], gn[4][4], bn[4][4];
#pragma unroll
  for (int m = 0; m < 4; ++m)
#pragma unroll
    for (int r = 0; r < 4; ++r) {
      int h = 16 * m + 4 * g + r;
      b1n[m][r] = ub1[h]; gn[m][r] = gam[h]; bn[m][r] = bet[h];
    }

  float s = 0.f;
#pragma unroll
  for (int m = 0; m < 4; ++m)
#pragma unroll
    for (int r = 0; r < 4; ++r) { un[m][r] += b1n[m][r]; s += un[m][r]; }
  s += __shfl_xor(s, 16);
  s += __shfl_xor(s, 32);
  const float mu = s * 0.015625f;
  float vs = 0.f;
#pragma unroll
  for (int m = 0; m < 4; ++m)
#pragma unroll
    for (int r = 0; r < 4; ++r) { float d = un[m][r] - mu; vs += d * d; }
  vs += __shfl_xor(vs, 16);
  vs += __shfl_xor(vs, 32);
  const float rstd = rsqrtf(vs * 0.015625f + 1e-5f);

  // LN -> leaky -> bf16 -> transposed H store (wave-private hbuf, edge use done)
#pragma unroll
  for (int m = 0; m < 4; ++m) {
    bf16x4 pk;
#pragma unroll
    for (int r = 0; r < 4; ++r)
      pk[r] = f2bf(lrelu((un[m][r] - mu) * rstd * gn[m][r] + bn[m][r]));
    const int byte = c * 128 + (((16 * m + 4 * g) * 2) ^ ((c & 7) << 4));
    *(bf16x4*)(hb + byte) = pk;
  }

  f32x4 ac[4];
#pragma unroll
  for (int n = 0; n < 4; ++n) ac[n] = f32x4{0.f, 0.f, 0.f, 0.f};
#pragma unroll
  for (int ks = 0; ks < 2; ++ks) {
    const int byte = c * 128 + ((ks * 64 + g * 16) ^ ((c & 7) << 4));
    bf16x8 hf = *(const bf16x8*)(hb + byte);
#pragma unroll
    for (int n = 0; n < 4; ++n) {
      bf16x8 wf = *(const bf16x8*)(uW2t + (size_t)(16 * n + c) * 64 + ks * 32 + g * 8);
      ac[n] = __builtin_amdgcn_mfma_f32_16x16x32_bf16(hf, wf, ac[n], 0, 0, 0);
    }
  }

  float b2n[4];
#pragma unroll
  for (int n = 0; n < 4; ++n) b2n[n] = ub2[16 * n + c];
#pragma unroll
  for (int r = 0; r < 4; ++r) {
    const int node = nb + 16 * wv + 4 * g + r;   // < NN always (3125*32 == NN)
    float* op = out + (size_t)node * 64 + c;
#pragma unroll
    for (int n = 0; n < 4; ++n) op[16 * n] = ac[n][r] + b2n[n];
  }
}

// ---------- fallback path (verbatim R1, fully proven incl. post-timing) ----------
__global__ __launch_bounds__(256) void edge_kernel(
    const float* __restrict__ nf, const int* __restrict__ ei,
    const float* __restrict__ ea, const float* __restrict__ ew,
    const short* __restrict__ W1t, const float* __restrict__ b1,
    const short* __restrict__ W2t, const float* __restrict__ b2,
    float* __restrict__ agg) {
  __shared__ uint4 hbuf_s[4][512];
  const int tid = threadIdx.x;
  const int wv = tid >> 6, ln = tid & 63;
  const int c = ln & 15, g = ln >> 4;
  char* hb = (char*)hbuf_s[wv];
  const long base = ((long)blockIdx.x * 4 + wv) * 64;

  int eid[4], srcn[4];
#pragma unroll
  for (int n = 0; n < 4; ++n) {
    eid[n] = (int)base + 16 * n + c;
    srcn[n] = ei[eid[n]];
  }
  f32x4 acc1[4][4];
#pragma unroll
  for (int i = 0; i < 4; ++i)
#pragma unroll
    for (int j = 0; j < 4; ++j) acc1[i][j] = f32x4{0.f, 0.f, 0.f, 0.f};
#pragma unroll
  for (int ks = 0; ks < 3; ++ks) {
    bf16x8 xf[4];
#pragma unroll
    for (int n = 0; n < 4; ++n) {
      const float* p = (ks < 2) ? (nf + (size_t)srcn[n] * 64 + ks * 32 + g * 8)
                                : (ea + (size_t)eid[n] * 32 + g * 8);
      float4 u = *(const float4*)p;
      float4 v = *(const float4*)(p + 4);
      bf16x8 t;
      t[0] = f2bf(u.x); t[1] = f2bf(u.y); t[2] = f2bf(u.z); t[3] = f2bf(u.w);
      t[4] = f2bf(v.x); t[5] = f2bf(v.y); t[6] = f2bf(v.z); t[7] = f2bf(v.w);
      xf[n] = t;
    }
#pragma unroll
    for (int m = 0; m < 4; ++m) {
      bf16x8 wf = *(const bf16x8*)(W1t + (size_t)(16 * m + c) * 96 + ks * 32 + g * 8);
#pragma unroll
      for (int n = 0; n < 4; ++n)
        acc1[m][n] = __builtin_amdgcn_mfma_f32_16x16x32_bf16(wf, xf[n], acc1[m][n], 0, 0, 0);
    }
  }
  float b1v[4][4];
#pragma unroll
  for (int m = 0; m < 4; ++m)
#pragma unroll
    for (int r = 0; r < 4; ++r) b1v[m][r] = b1[16 * m + 4 * g + r];
#pragma unroll
  for (int m = 0; m < 4; ++m) {
    const int h0 = 16 * m + 4 * g;
#pragma unroll
    for (int n = 0; n < 4; ++n) {
      const int e = 16 * n + c;
      bf16x4 pk;
#pragma unroll
      for (int r = 0; r < 4; ++r) pk[r] = f2bf(lrelu(acc1[m][n][r] + b1v[m][r]));
      const int byte = e * 128 + ((h0 * 2) ^ ((e & 7) << 4));
      *(bf16x4*)(hb + byte) = pk;
    }
  }
  f32x4 acc2[4][4];
#pragma unroll
  for (int i = 0; i < 4; ++i)
#pragma unroll
    for (int j = 0; j < 4; ++j) acc2[i][j] = f32x4{0.f, 0.f, 0.f, 0.f};
#pragma unroll
  for (int ks = 0; ks < 2; ++ks) {
    bf16x8 hf[4];
#pragma unroll
    for (int m = 0; m < 4; ++m) {
      const int e = 16 * m + c;
      const int byte = e * 128 + ((ks * 64 + g * 16) ^ ((e & 7) << 4));
      hf[m] = *(const bf16x8*)(hb + byte);
    }
#pragma unroll
    for (int n = 0; n < 4; ++n) {
      bf16x8 wf = *(const bf16x8*)(W2t + (size_t)(16 * n + c) * 64 + ks * 32 + g * 8);
#pragma unroll
      for (int m = 0; m < 4; ++m)
        acc2[m][n] = __builtin_amdgcn_mfma_f32_16x16x32_bf16(hf[m], wf, acc2[m][n], 0, 0, 0);
    }
  }
  float b2v[4];
#pragma unroll
  for (int n = 0; n < 4; ++n) b2v[n] = b2[16 * n + c];
#pragma unroll
  for (int m = 0; m < 4; ++m)
#pragma unroll
    for (int r = 0; r < 4; ++r) {
      const long e = base + 16 * m + 4 * g + r;
      const float w = ew[e];
      const int dst = ei[NE + e];
      float* ab = agg + (size_t)dst * 64 + c;
#pragma unroll
      for (int n = 0; n < 4; ++n)
        atomic_add_f32(ab + 16 * n, (acc2[m][n][r] + b2v[n]) * w);
    }
}

__global__ __launch_bounds__(256) void node_kernel(
    const float* __restrict__ nf,
    const short* __restrict__ W1t, const float* __restrict__ b1,
    const float* __restrict__ gam, const float* __restrict__ bet,
    const short* __restrict__ W2t, const float* __restrict__ b2,
    float* __restrict__ io) {
  __shared__ uint4 hbuf_s[4][512];
  const int tid = threadIdx.x;
  const int wv = tid >> 6, ln = tid & 63;
  const int c = ln & 15, g = ln >> 4;
  char* hb = (char*)hbuf_s[wv];
  const long base = ((long)blockIdx.x * 4 + wv) * 64;

  int nid[4];
#pragma unroll
  for (int n = 0; n < 4; ++n) {
    long r = base + 16 * n + c;
    nid[n] = (r < NN) ? (int)r : (NN - 1);
  }
  f32x4 acc1[4][4];
#pragma unroll
  for (int i = 0; i < 4; ++i)
#pragma unroll
    for (int j = 0; j < 4; ++j) acc1[i][j] = f32x4{0.f, 0.f, 0.f, 0.f};
#pragma unroll
  for (int ks = 0; ks < 4; ++ks) {
    bf16x8 xf[4];
#pragma unroll
    for (int n = 0; n < 4; ++n) {
      const float* p = (ks < 2) ? (nf + (size_t)nid[n] * 64 + ks * 32 + g * 8)
                                : (io + (size_t)nid[n] * 64 + (ks - 2) * 32 + g * 8);
      float4 u = *(const float4*)p;
      float4 v = *(const float4*)(p + 4);
      bf16x8 t;
      t[0] = f2bf(u.x); t[1] = f2bf(u.y); t[2] = f2bf(u.z); t[3] = f2bf(u.w);
      t[4] = f2bf(v.x); t[5] = f2bf(v.y); t[6] = f2bf(v.z); t[7] = f2bf(v.w);
      xf[n] = t;
    }
#pragma unroll
    for (int m = 0; m < 4; ++m) {
      bf16x8 wf = *(const bf16x8*)(W1t + (size_t)(16 * m + c) * 128 + ks * 32 + g * 8);
#pragma unroll
      for (int n = 0; n < 4; ++n)
        acc1[m][n] = __builtin_amdgcn_mfma_f32_16x16x32_bf16(wf, xf[n], acc1[m][n], 0, 0, 0);
    }
  }
  float b1v[4][4], gv[4][4], bv[4][4];
#pragma unroll
  for (int m = 0; m < 4; ++m)
#pragma unroll
    for (int r = 0; r < 4; ++r) {
      int h = 16 * m + 4 * g + r;
      b1v[m][r] = b1[h]; gv[m][r] = gam[h]; bv[m][r] = bet[h];
    }
#pragma unroll
  for (int n = 0; n < 4; ++n) {
    float s = 0.f;
#pragma unroll
    for (int m = 0; m < 4; ++m)
#pragma unroll
      for (int r = 0; r < 4; ++r) { acc1[m][n][r] += b1v[m][r]; s += acc1[m][n][r]; }
    s += __shfl_xor(s, 16);
    s += __shfl_xor(s, 32);
    const float mu = s * 0.015625f;
    float vs = 0.f;
#pragma unroll
    for (int m = 0; m < 4; ++m)
#pragma unroll
      for (int r = 0; r < 4; ++r) { float d = acc1[m][n][r] - mu; vs += d * d; }
    vs += __shfl_xor(vs, 16);
    vs += __shfl_xor(vs, 32);
    const float rstd = rsqrtf(vs * 0.015625f + 1e-5f);
    const int e = 16 * n + c;
#pragma unroll
    for (int m = 0; m < 4; ++m) {
      bf16x4 pk;
#pragma unroll
      for (int r = 0; r < 4; ++r)
        pk[r] = f2bf(lrelu((acc1[m][n][r] - mu) * rstd * gv[m][r] + bv[m][r]));
      const int byte = e * 128 + (((16 * m + 4 * g) * 2) ^ ((e & 7) << 4));
      *(bf16x4*)(hb + byte) = pk;
    }
  }
  f32x4 acc2[4][4];
#pragma unroll
  for (int i = 0; i < 4; ++i)
#pragma unroll
    for (int j = 0; j < 4; ++j) acc2[i][j] = f32x4{0.f, 0.f, 0.f, 0.f};
#pragma unroll
  for (int ks = 0; ks < 2; ++ks) {
    bf16x8 hf[4];
#pragma unroll
    for (int m = 0; m < 4; ++m) {
      const int e = 16 * m + c;
      const int byte = e * 128 + ((ks * 64 + g * 16) ^ ((e & 7) << 4));
      hf[m] = *(const bf16x8*)(hb + byte);
    }
#pragma unroll
    for (int n = 0; n < 4; ++n) {
      bf16x8 wf = *(const bf16x8*)(W2t + (size_t)(16 * n + c) * 64 + ks * 32 + g * 8);
#pragma unroll
      for (int m = 0; m < 4; ++m)
        acc2[m][n] = __builtin_amdgcn_mfma_f32_16x16x32_bf16(hf[m], wf, acc2[m][n], 0, 0, 0);
    }
  }
  float b2v[4];
#pragma unroll
  for (int n = 0; n < 4; ++n) b2v[n] = b2[16 * n + c];
#pragma unroll
  for (int m = 0; m < 4; ++m)
#pragma unroll
    for (int r = 0; r < 4; ++r) {
      const long node = base + 16 * m + 4 * g + r;
      if (node < NN) {
        float* op = io + (size_t)node * 64 + c;
#pragma unroll
        for (int n = 0; n < 4; ++n) op[16 * n] = acc2[m][n][r] + b2v[n];
      }
    }
}

extern "C" void kernel_launch(void* const* d_in, const int* in_sizes, int n_in,
                              void* d_out, int out_size, void* d_ws, size_t ws_size,
                              hipStream_t stream) {
  const float* nf  = (const float*)d_in[0];
  const int*   ei  = (const int*)d_in[1];
  const float* ea  = (const float*)d_in[2];
  const float* ew  = (const float*)d_in[3];
  const float* mW1 = (const float*)d_in[4];
  const float* mb1 = (const float*)d_in[5];
  const float* mW2 = (const float*)d_in[6];
  const float* mb2 = (const float*)d_in[7];
  const float* uW1 = (const float*)d_in[8];
  const float* ub1 = (const float*)d_in[9];
  const float* lng = (const float*)d_in[10];
  const float* lnb = (const float*)d_in[11];
  const float* uW2 = (const float*)d_in[12];
  const float* ub2 = (const float*)d_in[13];
  float* io = (float*)d_out;
  char* ws = (char*)d_ws;

  short* Wall = (short*)(ws + OFF_W);
  prep_kernel<<<88, 256, 0, stream>>>(mW1, mW2, uW1, uW2, Wall);
  const short* W1t  = Wall;
  const short* W2t  = Wall + 64 * 96;
  const short* uW1t = Wall + 64 * 96 + 64 * 64;
  const short* uW2t = uW1t + 64 * 128;

  if (ws_size >= (size_t)WS_NEED) {
    int*  cnt  = (int*)(ws + OFF_CNT);
    int*  off  = (int*)(ws + OFF_OFF);
    int*  cur  = (int*)(ws + OFF_CUR);
    int*  bs   = (int*)(ws + OFF_BS);
    int2* sse  = (int2*)(ws + OFF_SE);
    int*  sdst = (int*)(ws + OFF_SD);

    hipMemsetAsync(cnt, 0, (size_t)NN * sizeof(int), stream);
    hist_kernel<<<NE / 256, 256, 0, stream>>>(ei, cnt);
    scan_block_kernel<<<98, 1024, 0, stream>>>(cnt, off, bs);
    scan_add_kernel<<<98, 1024, 0, stream>>>(off, bs, cur);
    scatter_kernel<<<NE / 256, 256, 0, stream>>>(ei, cur, sse, sdst);
    sortruns_kernel<<<(NN + 3) / 4, 256, 0, stream>>>(off, cnt, sse);
    fused_kernel<<<NN / 32, 128, 0, stream>>>(nf, ea, ew, sse, sdst, off,
                                              W1t, mb1, W2t, mb2,
                                              uW1t, ub1, lng, lnb, uW2t, ub2, io);
  } else {
    hipMemsetAsync(d_out, 0, (size_t)NN * 64 * sizeof(float), stream);
    edge_kernel<<<NE / 256, 256, 0, stream>>>(nf, ei, ea, ew, W1t, mb1, W2t, mb2, io);
    node_kernel<<<(NN + 255) / 256, 256, 0, stream>>>(nf, uW1t, ub1, lng, lnb, uW2t, ub2, io);
  }
}

// Round 8
// 405.858 us; speedup vs baseline: 2.3423x; 1.2695x over previous
//
#include <hip/hip_runtime.h>
#include <cstdint>
#include <cstddef>

#define NN 100000
#define NE 1600000

#define QSCALE 262144.0f            // 2^18 fixed point: exact-commutative agg
#define QINV   3.814697265625e-06f  // 2^-18

typedef __attribute__((ext_vector_type(8))) short bf16x8;
typedef __attribute__((ext_vector_type(4))) short bf16x4;
typedef __attribute__((ext_vector_type(4))) float f32x4;

// ---- d_ws byte layout (proven to fit since R2) ----
#define OFF_W    0u          // bf16 weights, 45056 B
#define OFF_CNT  45056u      // int counts[NN]
#define OFF_OFF  445056u     // int offsets[NN]
#define OFF_CUR  845120u     // int cursor[NN]
#define OFF_BS   1245120u    // int blocksums[128]
#define OFF_SE   1245632u    // int2 (src,eid)[NE]
#define OFF_SD   14045632u   // int dst[NE]
#define WS_NEED  20445632u

__device__ __forceinline__ short f2bf(float f) {
  uint32_t u = __builtin_bit_cast(uint32_t, f);
  u += 0x7FFFu + ((u >> 16) & 1u);   // RNE
  return (short)(u >> 16);
}

__device__ __forceinline__ float lrelu(float x) { return fmaxf(x, 0.1f * x); }

__device__ __forceinline__ void atomic_add_f32(float* p, float v) {
  __hip_atomic_fetch_add(p, v, __ATOMIC_RELAXED, __HIP_MEMORY_SCOPE_AGENT);
}

// Pre-transpose + bf16-convert weights: W1t[64][96], W2t[64][64], uW1t[64][128], uW2t[64][64]
__global__ void prep_kernel(const float* __restrict__ W1, const float* __restrict__ W2,
                            const float* __restrict__ uW1, const float* __restrict__ uW2,
                            short* __restrict__ ws) {
  int t = blockIdx.x * 256 + threadIdx.x;
  const int n1 = 64 * 96, n2 = 64 * 64, n3 = 64 * 128, n4 = 64 * 64;
  if (t < n1) { int c = t / 96, k = t % 96; ws[t] = f2bf(W1[k * 64 + c]); return; }
  t -= n1;
  if (t < n2) { int c = t / 64, k = t % 64; ws[n1 + t] = f2bf(W2[k * 64 + c]); return; }
  t -= n2;
  if (t < n3) { int c = t / 128, k = t % 128; ws[n1 + n2 + t] = f2bf(uW1[k * 64 + c]); return; }
  t -= n3;
  if (t < n4) { int c = t / 64, k = t % 64; ws[n1 + n2 + n3 + t] = f2bf(uW2[k * 64 + c]); return; }
}

// ---------- sort-by-dst machinery (R2/R7-proven) ----------
__global__ __launch_bounds__(256) void hist_kernel(const int* __restrict__ ei,
                                                   int* __restrict__ cnt) {
  int t = blockIdx.x * 256 + threadIdx.x;
  if (t < NE) atomicAdd(&cnt[ei[NE + t]], 1);
}

__global__ __launch_bounds__(1024) void scan_block_kernel(const int* __restrict__ cnt,
                                                          int* __restrict__ off,
                                                          int* __restrict__ bs) {
  __shared__ int wsum[16];
  const int tid = threadIdx.x, lane = tid & 63, w = tid >> 6;
  const int i = blockIdx.x * 1024 + tid;
  int v = (i < NN) ? cnt[i] : 0;
  int x = v;
#pragma unroll
  for (int d = 1; d < 64; d <<= 1) { int t = __shfl_up(x, d); if (lane >= d) x += t; }
  if (lane == 63) wsum[w] = x;
  __syncthreads();
  if (w == 0) {
    int s = (lane < 16) ? wsum[lane] : 0;
#pragma unroll
    for (int d = 1; d < 16; d <<= 1) { int t = __shfl_up(s, d); if (lane >= d) s += t; }
    if (lane < 16) wsum[lane] = s;
  }
  __syncthreads();
  int incl = x + ((w > 0) ? wsum[w - 1] : 0);
  if (i < NN) off[i] = incl - v;
  if (tid == 1023) bs[blockIdx.x] = incl;
}

__global__ __launch_bounds__(1024) void scan_add_kernel(int* __restrict__ off,
                                                        const int* __restrict__ bs,
                                                        int* __restrict__ cur) {
  __shared__ int sbase;
  const int tid = threadIdx.x, cB = blockIdx.x;
  if (tid < 64) {
    int s = 0;
    if (tid < cB && tid < 98) s += bs[tid];
    int j2 = tid + 64;
    if (j2 < cB && j2 < 98) s += bs[j2];
#pragma unroll
    for (int d = 1; d < 64; d <<= 1) s += __shfl_xor(s, d);
    if (tid == 0) sbase = s;
  }
  __syncthreads();
  const int base = sbase;
  const int i = cB * 1024 + tid;
  if (i < NN) { int o = off[i] + base; off[i] = o; cur[i] = o; }
}

__global__ __launch_bounds__(256) void scatter_kernel(const int* __restrict__ ei,
                                                      int* __restrict__ cur,
                                                      int2* __restrict__ sse,
                                                      int* __restrict__ sdst) {
  int t = blockIdx.x * 256 + threadIdx.x;
  if (t >= NE) return;
  int d = ei[NE + t];
  int pos = atomicAdd(&cur[d], 1);
  sse[pos] = make_int2(ei[t], t);
  sdst[pos] = d;
}

// ---------- fused kernel: block owns 32 dsts; edge MLP -> LDS int agg -> node MLP ----------
// d_out written EXACTLY ONCE per element; agg never leaves LDS (replay-safe,
// proven R2/R7). Int fixed-point agg => output invariant to the scatter
// permutation, so no run canonicalization is needed (R2 precedent).
// R8: meta prefetch (next tile's sse/sdst/ew issued before current compute)
// and shfl-derived src/eid (no per-n sse re-reads).
__global__ __launch_bounds__(128) void fused_kernel(
    const float* __restrict__ nf, const float* __restrict__ ea,
    const float* __restrict__ ew,
    const int2* __restrict__ sse, const int* __restrict__ sdst,
    const int* __restrict__ off,
    const short* __restrict__ W1t, const float* __restrict__ b1,
    const short* __restrict__ W2t, const float* __restrict__ b2,
    const short* __restrict__ uW1t, const float* __restrict__ ub1,
    const float* __restrict__ gam, const float* __restrict__ bet,
    const short* __restrict__ uW2t, const float* __restrict__ ub2,
    float* __restrict__ out) {
  __shared__ __align__(16) char hbuf[2][8192];   // per-wave H staging
  __shared__ int   sAgg[32 * 65];                // fixed-point agg [32 dst][64+1]
  __shared__ int   tdstS[2][64];
  __shared__ float twS[2][64];

  const int tid = threadIdx.x;
  const int wv = tid >> 6, ln = tid & 63;
  const int c = ln & 15, g = ln >> 4;
  char* hb = hbuf[wv];
  const int nb = blockIdx.x * 32;

  for (int i = tid; i < 32 * 65; i += 128) sAgg[i] = 0;

  const int e0 = off[nb];
  const int e1 = (nb + 32 >= NN) ? NE : off[nb + 32];
  __syncthreads();

  float b1v[4][4];
#pragma unroll
  for (int m = 0; m < 4; ++m)
#pragma unroll
    for (int r = 0; r < 4; ++r) b1v[m][r] = b1[16 * m + 4 * g + r];
  float b2v[4];
#pragma unroll
  for (int n = 0; n < 4; ++n) b2v[n] = b2[16 * n + c];

  // -------- edge phase: 64-edge tiles (waves interleaved), meta-prefetched --------
  int t0 = e0 + wv * 64;
  if (t0 < e1) {
    // meta for this lane's slot of the first tile
    int msx, msy, md; float mw;
    {
      int slot = t0 + ln;
      int cl = (slot < e1) ? slot : (e1 - 1);
      int2 se = sse[cl];
      msx = se.x; msy = se.y; md = sdst[cl]; mw = ew[se.y];
    }

    for (; t0 < e1; t0 += 128) {
      // stash current meta to LDS (masked) for the agg phase
      {
        bool val = (t0 + ln) < e1;
        tdstS[wv][ln] = val ? (md - nb) : 0;
        twS[wv][ln]   = val ? mw : 0.f;
      }
      // per-(n,c) src/eid via cross-lane shuffle of the meta registers
      int src[4], eid[4];
#pragma unroll
      for (int n = 0; n < 4; ++n) {
        src[n] = __shfl(msx, 16 * n + c);
        eid[n] = __shfl(msy, 16 * n + c);
      }

      // prefetch next tile's meta (issued before the heavy compute)
      int nsx = msx, nsy = msy, nd = md; float nw = mw;
      if (t0 + 128 < e1) {
        int slot = t0 + 128 + ln;
        int cl = (slot < e1) ? slot : (e1 - 1);
        int2 se = sse[cl];
        nsx = se.x; nsy = se.y; nd = sdst[cl]; nw = ew[se.y];
      }

      // GEMM1 (swapped): acc1 = W1^T x X^T
      f32x4 acc1[4][4];
#pragma unroll
      for (int i = 0; i < 4; ++i)
#pragma unroll
        for (int j = 0; j < 4; ++j) acc1[i][j] = f32x4{0.f, 0.f, 0.f, 0.f};

#pragma unroll
      for (int ks = 0; ks < 3; ++ks) {
        bf16x8 xf[4];
#pragma unroll
        for (int n = 0; n < 4; ++n) {
          const float* p = (ks < 2) ? (nf + (size_t)src[n] * 64 + ks * 32 + g * 8)
                                    : (ea + (size_t)eid[n] * 32 + g * 8);
          float4 u = *(const float4*)p;
          float4 v = *(const float4*)(p + 4);
          bf16x8 t;
          t[0] = f2bf(u.x); t[1] = f2bf(u.y); t[2] = f2bf(u.z); t[3] = f2bf(u.w);
          t[4] = f2bf(v.x); t[5] = f2bf(v.y); t[6] = f2bf(v.z); t[7] = f2bf(v.w);
          xf[n] = t;
        }
#pragma unroll
        for (int m = 0; m < 4; ++m) {
          bf16x8 wf = *(const bf16x8*)(W1t + (size_t)(16 * m + c) * 96 + ks * 32 + g * 8);
#pragma unroll
          for (int n = 0; n < 4; ++n)
            acc1[m][n] = __builtin_amdgcn_mfma_f32_16x16x32_bf16(wf, xf[n], acc1[m][n], 0, 0, 0);
        }
      }

      // bias + leaky + transposed H store (pitch 128, XOR swizzle; wave-private)
#pragma unroll
      for (int m = 0; m < 4; ++m) {
        const int h0 = 16 * m + 4 * g;
#pragma unroll
        for (int n = 0; n < 4; ++n) {
          const int e = 16 * n + c;
          bf16x4 pk;
#pragma unroll
          for (int r = 0; r < 4; ++r) pk[r] = f2bf(lrelu(acc1[m][n][r] + b1v[m][r]));
          const int byte = e * 128 + ((h0 * 2) ^ ((e & 7) << 4));
          *(bf16x4*)(hb + byte) = pk;
        }
      }

      // GEMM2: acc2 = H x W2 (rows=edges, cols=dims)
      f32x4 acc2[4][4];
#pragma unroll
      for (int i = 0; i < 4; ++i)
#pragma unroll
        for (int j = 0; j < 4; ++j) acc2[i][j] = f32x4{0.f, 0.f, 0.f, 0.f};
#pragma unroll
      for (int ks = 0; ks < 2; ++ks) {
        bf16x8 hf[4];
#pragma unroll
        for (int m = 0; m < 4; ++m) {
          const int e = 16 * m + c;
          const int byte = e * 128 + ((ks * 64 + g * 16) ^ ((e & 7) << 4));
          hf[m] = *(const bf16x8*)(hb + byte);
        }
#pragma unroll
        for (int n = 0; n < 4; ++n) {
          bf16x8 wf = *(const bf16x8*)(W2t + (size_t)(16 * n + c) * 64 + ks * 32 + g * 8);
#pragma unroll
          for (int m = 0; m < 4; ++m)
            acc2[m][n] = __builtin_amdgcn_mfma_f32_16x16x32_bf16(hf[m], wf, acc2[m][n], 0, 0, 0);
        }
      }

      // aggregate: quantize once, LDS int atomics (exact-commutative)
#pragma unroll
      for (int m = 0; m < 4; ++m)
#pragma unroll
        for (int r = 0; r < 4; ++r) {
          const int el = 16 * m + 4 * g + r;
          const int dl = tdstS[wv][el];
          const float w = twS[wv][el];
#pragma unroll
          for (int n = 0; n < 4; ++n)
            atomicAdd(&sAgg[dl * 65 + 16 * n + c],
                      __float2int_rn((acc2[m][n][r] + b2v[n]) * w * QSCALE));
        }

      msx = nsx; msy = nsy; md = nd; mw = nw;
    }
  }
  __syncthreads();   // all agg atomics complete; sAgg final

  // -------- node phase: wave wv owns 16 nodes [nb+16wv, nb+16wv+16) --------
  const int nodeN = nb + 16 * wv + c;

  f32x4 un[4];
#pragma unroll
  for (int m = 0; m < 4; ++m) un[m] = f32x4{0.f, 0.f, 0.f, 0.f};

#pragma unroll
  for (int ks = 0; ks < 4; ++ks) {
    bf16x8 xf;
    if (ks < 2) {
      const float* p = nf + (size_t)nodeN * 64 + ks * 32 + g * 8;
      float4 u = *(const float4*)p;
      float4 v = *(const float4*)(p + 4);
      xf[0] = f2bf(u.x); xf[1] = f2bf(u.y); xf[2] = f2bf(u.z); xf[3] = f2bf(u.w);
      xf[4] = f2bf(v.x); xf[5] = f2bf(v.y); xf[6] = f2bf(v.z); xf[7] = f2bf(v.w);
    } else {
      const int* p = sAgg + (16 * wv + c) * 65 + (ks - 2) * 32 + g * 8;
#pragma unroll
      for (int j = 0; j < 8; ++j) xf[j] = f2bf((float)p[j] * QINV);
    }
#pragma unroll
    for (int m = 0; m < 4; ++m) {
      bf16x8 wf = *(const bf16x8*)(uW1t + (size_t)(16 * m + c) * 128 + ks * 32 + g * 8);
      un[m] = __builtin_amdgcn_mfma_f32_16x16x32_bf16(wf, xf, un[m], 0, 0, 0);
    }
  }

  float b1n[4][4], gn[4][4], bn[4][4];
#pragma unroll
  for (int m = 0; m < 4; ++m)
#pragma unroll
    for (int r = 0; r < 4; ++r) {
      int h = 16 * m + 4 * g + r;
      b1n[m][r] = ub1[h]; gn[m][r] = gam[h]; bn[m][r] = bet[h];
    }

  float s = 0.f;
#pragma unroll
  for (int m = 0; m < 4; ++m)
#pragma unroll
    for (int r = 0; r < 4; ++r) { un[m][r] += b1n[m][r]; s += un[m][r]; }
  s += __shfl_xor(s, 16);
  s += __shfl_xor(s, 32);
  const float mu = s * 0.015625f;
  float vs = 0.f;
#pragma unroll
  for (int m = 0; m < 4; ++m)
#pragma unroll
    for (int r = 0; r < 4; ++r) { float d = un[m][r] - mu; vs += d * d; }
  vs += __shfl_xor(vs, 16);
  vs += __shfl_xor(vs, 32);
  const float rstd = rsqrtf(vs * 0.015625f + 1e-5f);

#pragma unroll
  for (int m = 0; m < 4; ++m) {
    bf16x4 pk;
#pragma unroll
    for (int r = 0; r < 4; ++r)
      pk[r] = f2bf(lrelu((un[m][r] - mu) * rstd * gn[m][r] + bn[m][r]));
    const int byte = c * 128 + (((16 * m + 4 * g) * 2) ^ ((c & 7) << 4));
    *(bf16x4*)(hb + byte) = pk;
  }

  f32x4 ac[4];
#pragma unroll
  for (int n = 0; n < 4; ++n) ac[n] = f32x4{0.f, 0.f, 0.f, 0.f};
#pragma unroll
  for (int ks = 0; ks < 2; ++ks) {
    const int byte = c * 128 + ((ks * 64 + g * 16) ^ ((c & 7) << 4));
    bf16x8 hf = *(const bf16x8*)(hb + byte);
#pragma unroll
    for (int n = 0; n < 4; ++n) {
      bf16x8 wf = *(const bf16x8*)(uW2t + (size_t)(16 * n + c) * 64 + ks * 32 + g * 8);
      ac[n] = __builtin_amdgcn_mfma_f32_16x16x32_bf16(hf, wf, ac[n], 0, 0, 0);
    }
  }

  float b2n[4];
#pragma unroll
  for (int n = 0; n < 4; ++n) b2n[n] = ub2[16 * n + c];
#pragma unroll
  for (int r = 0; r < 4; ++r) {
    const int node = nb + 16 * wv + 4 * g + r;   // < NN always (3125*32 == NN)
    float* op = out + (size_t)node * 64 + c;
#pragma unroll
    for (int n = 0; n < 4; ++n) op[16 * n] = ac[n][r] + b2n[n];
  }
}

// ---------- fallback path (verbatim R1, fully proven incl. post-timing) ----------
__global__ __launch_bounds__(256) void edge_kernel(
    const float* __restrict__ nf, const int* __restrict__ ei,
    const float* __restrict__ ea, const float* __restrict__ ew,
    const short* __restrict__ W1t, const float* __restrict__ b1,
    const short* __restrict__ W2t, const float* __restrict__ b2,
    float* __restrict__ agg) {
  __shared__ uint4 hbuf_s[4][512];
  const int tid = threadIdx.x;
  const int wv = tid >> 6, ln = tid & 63;
  const int c = ln & 15, g = ln >> 4;
  char* hb = (char*)hbuf_s[wv];
  const long base = ((long)blockIdx.x * 4 + wv) * 64;

  int eid[4], srcn[4];
#pragma unroll
  for (int n = 0; n < 4; ++n) {
    eid[n] = (int)base + 16 * n + c;
    srcn[n] = ei[eid[n]];
  }
  f32x4 acc1[4][4];
#pragma unroll
  for (int i = 0; i < 4; ++i)
#pragma unroll
    for (int j = 0; j < 4; ++j) acc1[i][j] = f32x4{0.f, 0.f, 0.f, 0.f};
#pragma unroll
  for (int ks = 0; ks < 3; ++ks) {
    bf16x8 xf[4];
#pragma unroll
    for (int n = 0; n < 4; ++n) {
      const float* p = (ks < 2) ? (nf + (size_t)srcn[n] * 64 + ks * 32 + g * 8)
                                : (ea + (size_t)eid[n] * 32 + g * 8);
      float4 u = *(const float4*)p;
      float4 v = *(const float4*)(p + 4);
      bf16x8 t;
      t[0] = f2bf(u.x); t[1] = f2bf(u.y); t[2] = f2bf(u.z); t[3] = f2bf(u.w);
      t[4] = f2bf(v.x); t[5] = f2bf(v.y); t[6] = f2bf(v.z); t[7] = f2bf(v.w);
      xf[n] = t;
    }
#pragma unroll
    for (int m = 0; m < 4; ++m) {
      bf16x8 wf = *(const bf16x8*)(W1t + (size_t)(16 * m + c) * 96 + ks * 32 + g * 8);
#pragma unroll
      for (int n = 0; n < 4; ++n)
        acc1[m][n] = __builtin_amdgcn_mfma_f32_16x16x32_bf16(wf, xf[n], acc1[m][n], 0, 0, 0);
    }
  }
  float b1v[4][4];
#pragma unroll
  for (int m = 0; m < 4; ++m)
#pragma unroll
    for (int r = 0; r < 4; ++r) b1v[m][r] = b1[16 * m + 4 * g + r];
#pragma unroll
  for (int m = 0; m < 4; ++m) {
    const int h0 = 16 * m + 4 * g;
#pragma unroll
    for (int n = 0; n < 4; ++n) {
      const int e = 16 * n + c;
      bf16x4 pk;
#pragma unroll
      for (int r = 0; r < 4; ++r) pk[r] = f2bf(lrelu(acc1[m][n][r] + b1v[m][r]));
      const int byte = e * 128 + ((h0 * 2) ^ ((e & 7) << 4));
      *(bf16x4*)(hb + byte) = pk;
    }
  }
  f32x4 acc2[4][4];
#pragma unroll
  for (int i = 0; i < 4; ++i)
#pragma unroll
    for (int j = 0; j < 4; ++j) acc2[i][j] = f32x4{0.f, 0.f, 0.f, 0.f};
#pragma unroll
  for (int ks = 0; ks < 2; ++ks) {
    bf16x8 hf[4];
#pragma unroll
    for (int m = 0; m < 4; ++m) {
      const int e = 16 * m + c;
      const int byte = e * 128 + ((ks * 64 + g * 16) ^ ((e & 7) << 4));
      hf[m] = *(const bf16x8*)(hb + byte);
    }
#pragma unroll
    for (int n = 0; n < 4; ++n) {
      bf16x8 wf = *(const bf16x8*)(W2t + (size_t)(16 * n + c) * 64 + ks * 32 + g * 8);
#pragma unroll
      for (int m = 0; m < 4; ++m)
        acc2[m][n] = __builtin_amdgcn_mfma_f32_16x16x32_bf16(hf[m], wf, acc2[m][n], 0, 0, 0);
    }
  }
  float b2v[4];
#pragma unroll
  for (int n = 0; n < 4; ++n) b2v[n] = b2[16 * n + c];
#pragma unroll
  for (int m = 0; m < 4; ++m)
#pragma unroll
    for (int r = 0; r < 4; ++r) {
      const long e = base + 16 * m + 4 * g + r;
      const float w = ew[e];
      const int dst = ei[NE + e];
      float* ab = agg + (size_t)dst * 64 + c;
#pragma unroll
      for (int n = 0; n < 4; ++n)
        atomic_add_f32(ab + 16 * n, (acc2[m][n][r] + b2v[n]) * w);
    }
}

__global__ __launch_bounds__(256) void node_kernel(
    const float* __restrict__ nf,
    const short* __restrict__ W1t, const float* __restrict__ b1,
    const float* __restrict__ gam, const float* __restrict__ bet,
    const short* __restrict__ W2t, const float* __restrict__ b2,
    float* __restrict__ io) {
  __shared__ uint4 hbuf_s[4][512];
  const int tid = threadIdx.x;
  const int wv = tid >> 6, ln = tid & 63;
  const int c = ln & 15, g = ln >> 4;
  char* hb = (char*)hbuf_s[wv];
  const long base = ((long)blockIdx.x * 4 + wv) * 64;

  int nid[4];
#pragma unroll
  for (int n = 0; n < 4; ++n) {
    long r = base + 16 * n + c;
    nid[n] = (r < NN) ? (int)r : (NN - 1);
  }
  f32x4 acc1[4][4];
#pragma unroll
  for (int i = 0; i < 4; ++i)
#pragma unroll
    for (int j = 0; j < 4; ++j) acc1[i][j] = f32x4{0.f, 0.f, 0.f, 0.f};
#pragma unroll
  for (int ks = 0; ks < 4; ++ks) {
    bf16x8 xf[4];
#pragma unroll
    for (int n = 0; n < 4; ++n) {
      const float* p = (ks < 2) ? (nf + (size_t)nid[n] * 64 + ks * 32 + g * 8)
                                : (io + (size_t)nid[n] * 64 + (ks - 2) * 32 + g * 8);
      float4 u = *(const float4*)p;
      float4 v = *(const float4*)(p + 4);
      bf16x8 t;
      t[0] = f2bf(u.x); t[1] = f2bf(u.y); t[2] = f2bf(u.z); t[3] = f2bf(u.w);
      t[4] = f2bf(v.x); t[5] = f2bf(v.y); t[6] = f2bf(v.z); t[7] = f2bf(v.w);
      xf[n] = t;
    }
#pragma unroll
    for (int m = 0; m < 4; ++m) {
      bf16x8 wf = *(const bf16x8*)(W1t + (size_t)(16 * m + c) * 128 + ks * 32 + g * 8);
#pragma unroll
      for (int n = 0; n < 4; ++n)
        acc1[m][n] = __builtin_amdgcn_mfma_f32_16x16x32_bf16(wf, xf[n], acc1[m][n], 0, 0, 0);
    }
  }
  float b1v[4][4], gv[4][4], bv[4][4];
#pragma unroll
  for (int m = 0; m < 4; ++m)
#pragma unroll
    for (int r = 0; r < 4; ++r) {
      int h = 16 * m + 4 * g + r;
      b1v[m][r] = b1[h]; gv[m][r] = gam[h]; bv[m][r] = bet[h];
    }
#pragma unroll
  for (int n = 0; n < 4; ++n) {
    float s = 0.f;
#pragma unroll
    for (int m = 0; m < 4; ++m)
#pragma unroll
      for (int r = 0; r < 4; ++r) { acc1[m][n][r] += b1v[m][r]; s += acc1[m][n][r]; }
    s += __shfl_xor(s, 16);
    s += __shfl_xor(s, 32);
    const float mu = s * 0.015625f;
    float vs = 0.f;
#pragma unroll
    for (int m = 0; m < 4; ++m)
#pragma unroll
      for (int r = 0; r < 4; ++r) { float d = acc1[m][n][r] - mu; vs += d * d; }
    vs += __shfl_xor(vs, 16);
    vs += __shfl_xor(vs, 32);
    const float rstd = rsqrtf(vs * 0.015625f + 1e-5f);
    const int e = 16 * n + c;
#pragma unroll
    for (int m = 0; m < 4; ++m) {
      bf16x4 pk;
#pragma unroll
      for (int r = 0; r < 4; ++r)
        pk[r] = f2bf(lrelu((acc1[m][n][r] - mu) * rstd * gv[m][r] + bv[m][r]));
      const int byte = e * 128 + (((16 * m + 4 * g) * 2) ^ ((e & 7) << 4));
      *(bf16x4*)(hb + byte) = pk;
    }
  }
  f32x4 acc2[4][4];
#pragma unroll
  for (int i = 0; i < 4; ++i)
#pragma unroll
    for (int j = 0; j < 4; ++j) acc2[i][j] = f32x4{0.f, 0.f, 0.f, 0.f};
#pragma unroll
  for (int ks = 0; ks < 2; ++ks) {
    bf16x8 hf[4];
#pragma unroll
    for (int m = 0; m < 4; ++m) {
      const int e = 16 * m + c;
      const int byte = e * 128 + ((ks * 64 + g * 16) ^ ((e & 7) << 4));
      hf[m] = *(const bf16x8*)(hb + byte);
    }
#pragma unroll
    for (int n = 0; n < 4; ++n) {
      bf16x8 wf = *(const bf16x8*)(W2t + (size_t)(16 * n + c) * 64 + ks * 32 + g * 8);
#pragma unroll
      for (int m = 0; m < 4; ++m)
        acc2[m][n] = __builtin_amdgcn_mfma_f32_16x16x32_bf16(hf[m], wf, acc2[m][n], 0, 0, 0);
    }
  }
  float b2v[4];
#pragma unroll
  for (int n = 0; n < 4; ++n) b2v[n] = b2[16 * n + c];
#pragma unroll
  for (int m = 0; m < 4; ++m)
#pragma unroll
    for (int r = 0; r < 4; ++r) {
      const long node = base + 16 * m + 4 * g + r;
      if (node < NN) {
        float* op = io + (size_t)node * 64 + c;
#pragma unroll
        for (int n = 0; n < 4; ++n) op[16 * n] = acc2[m][n][r] + b2v[n];
      }
    }
}

extern "C" void kernel_launch(void* const* d_in, const int* in_sizes, int n_in,
                              void* d_out, int out_size, void* d_ws, size_t ws_size,
                              hipStream_t stream) {
  const float* nf  = (const float*)d_in[0];
  const int*   ei  = (const int*)d_in[1];
  const float* ea  = (const float*)d_in[2];
  const float* ew  = (const float*)d_in[3];
  const float* mW1 = (const float*)d_in[4];
  const float* mb1 = (const float*)d_in[5];
  const float* mW2 = (const float*)d_in[6];
  const float* mb2 = (const float*)d_in[7];
  const float* uW1 = (const float*)d_in[8];
  const float* ub1 = (const float*)d_in[9];
  const float* lng = (const float*)d_in[10];
  const float* lnb = (const float*)d_in[11];
  const float* uW2 = (const float*)d_in[12];
  const float* ub2 = (const float*)d_in[13];
  float* io = (float*)d_out;
  char* ws = (char*)d_ws;

  short* Wall = (short*)(ws + OFF_W);
  prep_kernel<<<88, 256, 0, stream>>>(mW1, mW2, uW1, uW2, Wall);
  const short* W1t  = Wall;
  const short* W2t  = Wall + 64 * 96;
  const short* uW1t = Wall + 64 * 96 + 64 * 64;
  const short* uW2t = uW1t + 64 * 128;

  if (ws_size >= (size_t)WS_NEED) {
    int*  cnt  = (int*)(ws + OFF_CNT);
    int*  off  = (int*)(ws + OFF_OFF);
    int*  cur  = (int*)(ws + OFF_CUR);
    int*  bs   = (int*)(ws + OFF_BS);
    int2* sse  = (int2*)(ws + OFF_SE);
    int*  sdst = (int*)(ws + OFF_SD);

    hipMemsetAsync(cnt, 0, (size_t)NN * sizeof(int), stream);
    hist_kernel<<<NE / 256, 256, 0, stream>>>(ei, cnt);
    scan_block_kernel<<<98, 1024, 0, stream>>>(cnt, off, bs);
    scan_add_kernel<<<98, 1024, 0, stream>>>(off, bs, cur);
    scatter_kernel<<<NE / 256, 256, 0, stream>>>(ei, cur, sse, sdst);
    fused_kernel<<<NN / 32, 128, 0, stream>>>(nf, ea, ew, sse, sdst, off,
                                              W1t, mb1, W2t, mb2,
                                              uW1t, ub1, lng, lnb, uW2t, ub2, io);
  } else {
    hipMemsetAsync(d_out, 0, (size_t)NN * 64 * sizeof(float), stream);
    edge_kernel<<<NE / 256, 256, 0, stream>>>(nf, ei, ea, ew, W1t, mb1, W2t, mb2, io);
    node_kernel<<<(NN + 255) / 256, 256, 0, stream>>>(nf, uW1t, ub1, lng, lnb, uW2t, ub2, io);
  }
}